// Round 1
// baseline (577.393 us; speedup 1.0000x reference)
//
#include <hip/hip_runtime.h>
#include <hip/hip_bf16.h>
#include <math.h>

// ---------------- graph preprocessing ----------------

__global__ void k_hist(const int* __restrict__ dst, int E, int* __restrict__ deg) {
    int e = blockIdx.x * 256 + threadIdx.x;
    if (e < E) atomicAdd(&deg[dst[e]], 1);
}

__global__ void k_scan_sum(const int* __restrict__ deg, int n, int* __restrict__ blksum) {
    __shared__ int sd[256];
    int t = threadIdx.x;
    int base = blockIdx.x * 1024 + t * 4;
    int s = 0;
    if (base + 3 < n) {
        int4 v = *(const int4*)(deg + base);
        s = v.x + v.y + v.z + v.w;
    } else {
        for (int j = 0; j < 4; ++j) if (base + j < n) s += deg[base + j];
    }
    sd[t] = s; __syncthreads();
    for (int o = 128; o > 0; o >>= 1) {
        if (t < o) sd[t] += sd[t + o];
        __syncthreads();
    }
    if (t == 0) blksum[blockIdx.x] = sd[0];
}

__global__ void k_scan_blk(int* blksum, int nb) {
    // single thread serial exclusive scan (nb ~ 98)
    if (blockIdx.x == 0 && threadIdx.x == 0) {
        int run = 0;
        for (int i = 0; i < nb; ++i) { int v = blksum[i]; blksum[i] = run; run += v; }
    }
}

__global__ void k_scan_out(const int* __restrict__ deg, int n, const int* __restrict__ blkoff,
                           int* __restrict__ offsets, int* __restrict__ cursor,
                           float* __restrict__ dis, int E) {
    __shared__ int sa[256];
    __shared__ int sb[256];
    int t = threadIdx.x;
    int base = blockIdx.x * 1024 + t * 4;
    int v[4]; int s = 0;
    for (int j = 0; j < 4; ++j) {
        int idx = base + j;
        v[j] = (idx < n) ? deg[idx] : 0;
        s += v[j];
    }
    // Hillis-Steele inclusive scan of per-thread sums
    int* cur = sa; int* nxt = sb;
    cur[t] = s; __syncthreads();
    for (int o = 1; o < 256; o <<= 1) {
        int val = cur[t] + ((t >= o) ? cur[t - o] : 0);
        nxt[t] = val; __syncthreads();
        int* tmp = cur; cur = nxt; nxt = tmp;
    }
    int ex = cur[t] - s;  // exclusive prefix within block
    int run = blkoff[blockIdx.x] + ex;
    for (int j = 0; j < 4; ++j) {
        int idx = base + j;
        if (idx < n) {
            offsets[idx] = run;
            cursor[idx]  = run;
            dis[idx] = rsqrtf((float)v[j] + 1.0f);
            run += v[j];
        }
    }
    if (blockIdx.x == 0 && t == 0) offsets[n] = E;
}

__global__ void k_csr(const int* __restrict__ src, const int* __restrict__ dst, int E,
                      int* __restrict__ cursor, int* __restrict__ csr_src) {
    int e = blockIdx.x * 256 + threadIdx.x;
    if (e < E) {
        int d = dst[e];
        int p = atomicAdd(&cursor[d], 1);
        csr_src[p] = src[e];
    }
}

// ---------------- fused GEMM:  G = (A @ W) * dis[row] ----------------
// A: [M][128] row-major, W: [128][NCOL] row-major, G: [M][NCOL]
template<int NCOL>
__global__ __launch_bounds__(256, 1) void k_gemm_fused(
    const float* __restrict__ A, const float* __restrict__ W,
    const float* __restrict__ dis, float* __restrict__ G, int M)
{
    constexpr int K  = 128;
    constexpr int CG = NCOL / 8;     // col groups (16 or 8)
    constexpr int RG = 256 / CG;     // row groups (16 or 32)
    constexpr int TM = 128 / RG;     // rows per thread (8 or 4)
    constexpr int BR = 128;

    __shared__ float As[BR][K + 4];
    __shared__ float Ws[K][NCOL + 4];

    const int tid  = threadIdx.x;
    const int row0 = blockIdx.x * BR;
    const int cg   = tid & (CG - 1);
    const int rg   = tid / CG;

    // stage W (row-major, padded)
    for (int f = tid; f < K * NCOL / 4; f += 256) {
        int k  = f / (NCOL / 4);
        int cq = f % (NCOL / 4);
        float4 v = *(const float4*)(W + (size_t)k * NCOL + 4 * cq);
        *(float4*)(&Ws[k][4 * cq]) = v;
    }
    // stage A tile (row-major, padded)
    for (int f = tid; f < BR * K / 4; f += 256) {
        int r  = f >> 5;      // K/4 = 32
        int kq = f & 31;
        int row = row0 + r;
        float4 v;
        if (row < M) v = *(const float4*)(A + (size_t)row * K + 4 * kq);
        else         v = make_float4(0.f, 0.f, 0.f, 0.f);
        *(float4*)(&As[r][4 * kq]) = v;
    }
    __syncthreads();

    float acc[TM][8];
    #pragma unroll
    for (int i = 0; i < TM; ++i)
        #pragma unroll
        for (int c = 0; c < 8; ++c) acc[i][c] = 0.f;

    for (int k0 = 0; k0 < K; k0 += 4) {
        float4 af[TM];
        #pragma unroll
        for (int i = 0; i < TM; ++i)
            af[i] = *(const float4*)(&As[rg + RG * i][k0]);
        float bw[4][8];
        #pragma unroll
        for (int j = 0; j < 4; ++j)
            #pragma unroll
            for (int c = 0; c < 8; ++c)
                bw[j][c] = Ws[k0 + j][cg + CG * c];
        #pragma unroll
        for (int i = 0; i < TM; ++i)
            #pragma unroll
            for (int c = 0; c < 8; ++c) {
                acc[i][c] = fmaf(af[i].x, bw[0][c], acc[i][c]);
                acc[i][c] = fmaf(af[i].y, bw[1][c], acc[i][c]);
                acc[i][c] = fmaf(af[i].z, bw[2][c], acc[i][c]);
                acc[i][c] = fmaf(af[i].w, bw[3][c], acc[i][c]);
            }
    }

    #pragma unroll
    for (int i = 0; i < TM; ++i) {
        int row = row0 + rg + RG * i;
        if (row < M) {
            float dd = dis[row];
            #pragma unroll
            for (int c = 0; c < 8; ++c)
                G[(size_t)row * NCOL + cg + CG * c] = acc[i][c] * dd;
        }
    }
}

// ---------------- aggregation layer 1: y1 = relu(dis[d]*(sum g1[src] + g1[d]) + b1) ----------------
__global__ __launch_bounds__(256) void k_agg1(
    const float* __restrict__ g1, const int* __restrict__ offsets,
    const int* __restrict__ csr_src, const float* __restrict__ dis,
    const float* __restrict__ b1, float* __restrict__ y1, int n)
{
    int wid  = (blockIdx.x * 256 + threadIdx.x) >> 6;
    int lane = threadIdx.x & 63;
    if (wid >= n) return;
    int d = wid;
    int beg = offsets[d], end = offsets[d + 1];

    float2 acc = ((const float2*)(g1 + (size_t)d * 128))[lane];  // self term
    int j = beg;
    for (; j + 4 <= end; j += 4) {
        int s0 = csr_src[j], s1 = csr_src[j + 1], s2 = csr_src[j + 2], s3 = csr_src[j + 3];
        float2 v0 = ((const float2*)(g1 + (size_t)s0 * 128))[lane];
        float2 v1 = ((const float2*)(g1 + (size_t)s1 * 128))[lane];
        float2 v2 = ((const float2*)(g1 + (size_t)s2 * 128))[lane];
        float2 v3 = ((const float2*)(g1 + (size_t)s3 * 128))[lane];
        acc.x += v0.x + v1.x + v2.x + v3.x;
        acc.y += v0.y + v1.y + v2.y + v3.y;
    }
    for (; j < end; ++j) {
        int s = csr_src[j];
        float2 v = ((const float2*)(g1 + (size_t)s * 128))[lane];
        acc.x += v.x; acc.y += v.y;
    }
    float dd = dis[d];
    float2 bb = ((const float2*)b1)[lane];
    float2 o;
    o.x = fmaxf(fmaf(dd, acc.x, bb.x), 0.f);
    o.y = fmaxf(fmaf(dd, acc.y, bb.y), 0.f);
    ((float2*)(y1 + (size_t)d * 128))[lane] = o;
}

// ---------------- aggregation layer 2 + L2 normalize ----------------
__global__ __launch_bounds__(256) void k_agg2(
    const float* __restrict__ g2, const int* __restrict__ offsets,
    const int* __restrict__ csr_src, const float* __restrict__ dis,
    const float* __restrict__ b2, float* __restrict__ out, int n)
{
    int wid  = (blockIdx.x * 256 + threadIdx.x) >> 6;
    int lane = threadIdx.x & 63;
    if (wid >= n) return;
    int d = wid;
    int beg = offsets[d], end = offsets[d + 1];

    float acc = g2[(size_t)d * 64 + lane];  // self term
    int j = beg;
    for (; j + 4 <= end; j += 4) {
        int s0 = csr_src[j], s1 = csr_src[j + 1], s2 = csr_src[j + 2], s3 = csr_src[j + 3];
        float v0 = g2[(size_t)s0 * 64 + lane];
        float v1 = g2[(size_t)s1 * 64 + lane];
        float v2 = g2[(size_t)s2 * 64 + lane];
        float v3 = g2[(size_t)s3 * 64 + lane];
        acc += v0 + v1 + v2 + v3;
    }
    for (; j < end; ++j) {
        int s = csr_src[j];
        acc += g2[(size_t)s * 64 + lane];
    }
    float val = fmaf(dis[d], acc, b2[lane]);

    // L2 norm across the 64 lanes (one float per lane)
    float ss = val * val;
    #pragma unroll
    for (int o = 32; o >= 1; o >>= 1)
        ss += __shfl_xor(ss, o, 64);
    float norm = fmaxf(sqrtf(ss), 1e-12f);
    out[(size_t)d * 64 + lane] = val / norm;
}

// ---------------- launcher ----------------
extern "C" void kernel_launch(void* const* d_in, const int* in_sizes, int n_in,
                              void* d_out, int out_size, void* d_ws, size_t ws_size,
                              hipStream_t stream) {
    const float* x  = (const float*)d_in[0];
    const int*   ei = (const int*)d_in[1];
    const float* W1 = (const float*)d_in[2];
    const float* b1 = (const float*)d_in[3];
    const float* W2 = (const float*)d_in[4];
    const float* b2 = (const float*)d_in[5];

    const int N = in_sizes[0] / 128;   // 100000
    const int E = in_sizes[1] / 2;     // 1600000
    const int* src = ei;
    const int* dst = ei + E;

    char* ws = (char*)d_ws;
    size_t cur = 0;
    auto alloc = [&](size_t bytes) -> void* {
        void* p = ws + cur;
        cur += (bytes + 255) & ~(size_t)255;
        return p;
    };
    int*   deg     = (int*)  alloc((size_t)N * 4);
    int*   offsets = (int*)  alloc((size_t)(N + 1) * 4);
    int*   cursor  = (int*)  alloc((size_t)N * 4);
    int*   blks    = (int*)  alloc(4096);
    float* dis     = (float*)alloc((size_t)N * 4);
    int*   csr     = (int*)  alloc((size_t)E * 4);
    float* g1      = (float*)alloc((size_t)N * 128 * 4);
    float* y1      = (float*)alloc((size_t)N * 128 * 4);
    float* g2      = g1;  // g1 dead after agg1 -> reuse for layer-2 scaled features
    float* out     = (float*)d_out;

    const int nb = (N + 1023) / 1024;

    hipMemsetAsync(deg, 0, (size_t)N * 4, stream);
    k_hist<<<(E + 255) / 256, 256, 0, stream>>>(dst, E, deg);
    k_scan_sum<<<nb, 256, 0, stream>>>(deg, N, blks);
    k_scan_blk<<<1, 1, 0, stream>>>(blks, nb);
    k_scan_out<<<nb, 256, 0, stream>>>(deg, N, blks, offsets, cursor, dis, E);
    k_csr<<<(E + 255) / 256, 256, 0, stream>>>(src, dst, E, cursor, csr);

    // layer 1
    k_gemm_fused<128><<<(N + 127) / 128, 256, 0, stream>>>(x, W1, dis, g1, N);
    k_agg1<<<(N * 64 + 255) / 256, 256, 0, stream>>>(g1, offsets, csr, dis, b1, y1, N);

    // layer 2
    k_gemm_fused<64><<<(N + 127) / 128, 256, 0, stream>>>(y1, W2, dis, g2, N);
    k_agg2<<<(N * 64 + 255) / 256, 256, 0, stream>>>(g2, offsets, csr, dis, b2, out, N);
}